// Round 4
// baseline (1610.817 us; speedup 1.0000x reference)
//
#include <hip/hip_runtime.h>
#include <hip/hip_bf16.h>
#include <stdint.h>

// Problem constants
#define Bb 64
#define Qq 64
#define Tt 448
#define Dd 512
#define FDd 1024
#define Hh 8
#define NL 2
#define FFf 2048
#define Ss 512
#define DHh 64

typedef unsigned short u16;
typedef __bf16 bf16x8 __attribute__((ext_vector_type(8)));
typedef float f32x4 __attribute__((ext_vector_type(4)));
typedef u16 u16x4 __attribute__((ext_vector_type(4)));

__device__ __forceinline__ float bf2f(u16 u) { return __uint_as_float(((uint32_t)u) << 16); }
__device__ __forceinline__ u16 f2bfu(float f) {
    __bf16 h = (__bf16)f;
    return __builtin_bit_cast(unsigned short, h);
}
// Dual-mode load: input tensors may be bf16 (flag=1) or fp32 (flag=0)
__device__ __forceinline__ float ldx(const void* p, long i, int isbf) {
    return isbf ? bf2f(((const u16*)p)[i]) : ((const float*)p)[i];
}
// fast gelu: x*sigmoid(2c*x*(1+0.044715x^2)), c=0.79788456 (tanh-form, |err|<1e-3)
__device__ __forceinline__ float geluf(float v) {
    float u = v * (1.0f + 0.044715f * v * v) * -1.5957691216057308f;
    return v / (1.0f + __expf(u));
}
// async global->LDS, 16B per lane; lds ptr must be wave-uniform base (HW adds lane*16)
__device__ __forceinline__ void gload16(const void* g, void* l) {
    __builtin_amdgcn_global_load_lds((const __attribute__((address_space(1))) void*)g,
                                     (__attribute__((address_space(3))) void*)l, 16, 0, 0);
}
#define MFMA16(a, b, c) __builtin_amdgcn_mfma_f32_16x16x32_bf16(a, b, c, 0, 0, 0)

// ---------------- dtype probe ----------------
__global__ void probe_kernel(const void* pos_emb, int* flag) {
    if (threadIdx.x == 0) {
        uint32_t w = *(const uint32_t*)pos_emb;
        *flag = (w == 0x3F800000u) ? 1 : 0;
    }
}

// ---------------- convert (video -> canonical bf16; no-op when already bf16) -----------
__global__ void convert_kernel(const void* __restrict__ src, u16* __restrict__ dst, long n,
                               const int* __restrict__ flag) {
    const int isbf = *flag;
    if (isbf) return;  // video GEMM reads the original bf16 tensor directly
    long i = (long)blockIdx.x * blockDim.x + threadIdx.x;
    long stride = (long)gridDim.x * blockDim.x;
    for (; i < n; i += stride) {
        dst[i] = f2bfu(((const float*)src)[i]);
    }
}

// ---------------- dual-mode weight transpose: W[R,C] -> Wt[C,R] (bf16 out) -------------
__global__ void transpose_kernel(const void* __restrict__ src, u16* __restrict__ dst,
                                 int R, int C, long elem_off, const int* __restrict__ flag) {
    __shared__ u16 tile[32][33];
    const int isbf = *flag;
    const int c0 = blockIdx.x * 32, r0 = blockIdx.y * 32;
    const int tx = threadIdx.x, ty = threadIdx.y;
#pragma unroll
    for (int i = 0; i < 32; i += 8) {
        long idx = elem_off + (long)(r0 + ty + i) * C + (c0 + tx);
        tile[ty + i][tx] = isbf ? ((const u16*)src)[idx] : f2bfu(((const float*)src)[idx]);
    }
    __syncthreads();
#pragma unroll
    for (int i = 0; i < 32; i += 8) {
        dst[(long)(c0 + ty + i) * R + (r0 + tx)] = tile[tx][ty + i];
    }
}

// ---- batched 512x512 transpose: z selects {Wq,Wk,Wva,Wo} ------------------------------
__global__ void transpose4_kernel(const void* __restrict__ s0, const void* __restrict__ s1,
                                  const void* __restrict__ s2, const void* __restrict__ s3,
                                  u16* __restrict__ d0p, u16* __restrict__ d1p,
                                  u16* __restrict__ d2p, u16* __restrict__ d3p, long elem_off,
                                  const int* __restrict__ flag) {
    __shared__ u16 tile[32][33];
    const int isbf = *flag;
    const int z = blockIdx.z;
    const void* src = (z == 0) ? s0 : (z == 1) ? s1 : (z == 2) ? s2 : s3;
    u16* dst = (z == 0) ? d0p : (z == 1) ? d1p : (z == 2) ? d2p : d3p;
    const int c0 = blockIdx.x * 32, r0 = blockIdx.y * 32;
    const int tx = threadIdx.x, ty = threadIdx.y;
#pragma unroll
    for (int i = 0; i < 32; i += 8) {
        long idx = elem_off + (long)(r0 + ty + i) * Dd + (c0 + tx);
        tile[ty + i][tx] = isbf ? ((const u16*)src)[idx] : f2bfu(((const float*)src)[idx]);
    }
    __syncthreads();
#pragma unroll
    for (int i = 0; i < 32; i += 8) {
        dst[(long)(c0 + ty + i) * Dd + (r0 + tx)] = tile[tx][ty + i];
    }
}

// ================= 256x256 8-phase GEMM core, rotated reads + m-march ==================
// C[M,N] = A[M,K] @ Bt[N,K]^T + bias.
// MODE 0: bf16 out [M,NN]; MODE 1: + gelu; MODE 2: fused-QKV scatter epilogue.
// Rotated read schedule (counted lgkmcnt, T4 on the DS side): per kt,
//   ph0: issue {af0(8),bf0(4)} then {bf1(4)}; stage A(s+1); bar; lgkm(4);  q(0,0); bar
//   ph1: issue {ag(8)};                       stage A(s+1); bar; lgkm(8);  q(0,1); bar
//   ph2:                                      stage B(s+2); bar; lgkm(0);  q(1,0); bar
//   ph3:                                      stage B(s+2); bar;           q(1,1);
//        vmcnt(4) [counted, never 0 steady]; bar
// Fragment regs: af (MH0) and ag (MH1) are SEPARATE arrays (ag is written in ph1 while
// af is still live for q(0,1)). bfr[0]/bfr[1] never clobbered before last use.
// MSUB m-march: flat s-loop over MSUB m-tiles; staging continues across m-tile
// boundaries so epilogues overlap in-flight prefetch; one prologue per block.
// XCD-chunked remap (T1): xcd=bid&7 owns contiguous m-supertiles; n iterates fastest.
template <int MH>
__device__ __forceinline__ void ld_a(bf16x8 (&dst)[4][2], const u16* sa, int wm, int col16,
                                     int cp0, int cp1) {
#pragma unroll
    for (int mi = 0; mi < 4; mi++) {
        int rr = wm * 128 + MH * 64 + mi * 16 + col16;
        dst[mi][0] = *(const bf16x8*)&sa[rr * 64 + cp0 * 8];
        dst[mi][1] = *(const bf16x8*)&sa[rr * 64 + cp1 * 8];
    }
}
template <int NH>
__device__ __forceinline__ void ld_b(bf16x8 (&bfr)[2][2][2], const u16* sb, int wn, int col16,
                                     int cp0, int cp1) {
#pragma unroll
    for (int ni = 0; ni < 2; ni++) {
        int rr = wn * 64 + NH * 32 + ni * 16 + col16;
        bfr[NH][ni][0] = *(const bf16x8*)&sb[rr * 64 + cp0 * 8];
        bfr[NH][ni][1] = *(const bf16x8*)&sb[rr * 64 + cp1 * 8];
    }
}
template <int MH, int NH>
__device__ __forceinline__ void mma4(f32x4 (&acc)[8][4], const bf16x8 (&a)[4][2],
                                     const bf16x8 (&bfr)[2][2][2]) {
#pragma unroll
    for (int mi = 0; mi < 4; mi++)
#pragma unroll
        for (int ni = 0; ni < 2; ni++)
#pragma unroll
            for (int ks = 0; ks < 2; ks++)
                acc[MH * 4 + mi][NH * 2 + ni] =
                    MFMA16(a[mi][ks], bfr[NH][ni][ks], acc[MH * 4 + mi][NH * 2 + ni]);
}

#define PH_CNT(MH, NH, AARR, CNT)                             \
    __builtin_amdgcn_sched_barrier(0);                        \
    __builtin_amdgcn_s_barrier();                             \
    asm volatile("s_waitcnt lgkmcnt(" #CNT ")" ::: "memory"); \
    __builtin_amdgcn_sched_barrier(0);                        \
    __builtin_amdgcn_s_setprio(1);                            \
    mma4<MH, NH>(acc, AARR, bfr);                             \
    __builtin_amdgcn_s_setprio(0);                            \
    __builtin_amdgcn_sched_barrier(0);

template <int MODE, int KK, int NN, int MSUB>
__global__ __launch_bounds__(512) void gemm256(
    const u16* __restrict__ A, const void* __restrict__ Araw, const u16* __restrict__ Bt,
    const void* __restrict__ b0, const void* __restrict__ b1, const void* __restrict__ b2,
    long boff, void* __restrict__ o0, void* __restrict__ o1, void* __restrict__ o2, int M,
    const int* __restrict__ flag) {
    constexpr int NT = KK / 64;
    constexpr int TOT = NT * MSUB;
    constexpr int nbn = NN >> 8;
    __shared__ __align__(16) u16 sA2[2][16384];
    __shared__ __align__(16) u16 sB2[2][16384];
    const int tid = threadIdx.x;
    const int lane = tid & 63, wave = tid >> 6;
    const int wm = wave >> 2, wn = wave & 3;
    const int col16 = lane & 15, quad = lane >> 4;
    const int cp0 = quad ^ (col16 & 7);
    const int cp1 = cp0 ^ 4;
    const int isbf = *flag;
    const u16* Ap = (Araw && isbf) ? (const u16*)Araw : A;

    // XCD-chunked remap over m-supertiles (256*MSUB rows each), n fastest
    const int bid = blockIdx.x;
    const int xcd = bid & 7;
    const int loc = bid >> 3;
    const int nbm = M / (256 * MSUB);
    const int chunk = nbm >> 3;
    const int mloc = loc / nbn;
    const int nloc = loc - mloc * nbn;
    const long m0 = (long)(xcd * chunk + mloc) * (256L * MSUB);
    const long n0 = (long)nloc << 8;

    // staging: thread -> (row = q*64 + (tid>>3), 16B chunk slot tid&7, global chunk g)
    const int g = (tid & 7) ^ ((tid >> 3) & 7);
    const u16* agbase = Ap + (m0 + (tid >> 3)) * KK + g * 8;
    const u16* bgbase = Bt + (n0 + (tid >> 3)) * KK + g * 8;

    auto stA = [&](int s2, int q) {
        if (s2 < TOT) {
            const long mt = s2 / NT;
            const long k0 = (long)(s2 & (NT - 1)) * 64;
            gload16(agbase + mt * (256LL * KK) + (long)q * (64LL * KK) + k0,
                    &sA2[s2 & 1][q * 4096 + wave * 512]);
        }
    };
    auto stB = [&](int s2, int q) {
        if (s2 < TOT) {
            const long k0 = (long)(s2 & (NT - 1)) * 64;
            gload16(bgbase + (long)q * (64LL * KK) + k0, &sB2[s2 & 1][q * 4096 + wave * 512]);
        }
    };

    f32x4 acc[8][4];
#pragma unroll
    for (int i = 0; i < 8; i++)
#pragma unroll
        for (int j = 0; j < 4; j++) acc[i][j] = (f32x4){0.f, 0.f, 0.f, 0.f};

    // hoisted bias (loop-invariant)
    const void* bias;
    int region = 0;
    if constexpr (MODE == 2) {
        region = (int)(n0 >> 9);
        bias = (region == 0) ? b0 : (region == 1) ? b1 : b2;
    } else {
        bias = b0;
    }
    float bb[4];
#pragma unroll
    for (int ni = 0; ni < 4; ni++) {
        long col = n0 + wn * 64 + ni * 16 + col16;
        bb[ni] = ldx(bias, boff + (MODE == 2 ? (col & 511) : col), isbf);
    }

    // epilogue for one m-tile (runs inside the s-loop; prefetch stays in flight)
    auto epi = [&](int mt) {
        const long m0e = m0 + (long)mt * 256;
#pragma unroll
        for (int mi = 0; mi < 8; mi++) {
#pragma unroll
            for (int ni = 0; ni < 4; ni++) {
                long col = n0 + wn * 64 + ni * 16 + col16;
                if constexpr (MODE == 2) {
                    long cc = col & 511;
                    long h = cc >> 6, dh = cc & 63;
                    long row0 = m0e + wm * 128 + mi * 16 + quad * 4;
                    long b = row0 >> 9, s0 = row0 & 511;
                    if (region == 0) {
#pragma unroll
                        for (int r = 0; r < 4; r++)
                            ((u16*)o0)[(((b * 8 + h) * 512) + s0 + r) * 64 + dh] =
                                f2bfu((acc[mi][ni][r] + bb[ni]) * 0.125f);
                    } else if (region == 1) {
#pragma unroll
                        for (int r = 0; r < 4; r++)
                            ((u16*)o1)[(((b * 8 + h) * 512) + s0 + r) * 64 + dh] =
                                f2bfu(acc[mi][ni][r] + bb[ni]);
                    } else {  // v^T: 4 consecutive s for fixed dh -> one 8B store
                        u16x4 pk;
#pragma unroll
                        for (int r = 0; r < 4; r++) pk[r] = f2bfu(acc[mi][ni][r] + bb[ni]);
                        *(u16x4*)&((u16*)o2)[(((b * 8 + h) * 64) + dh) * 512 + s0] = pk;
                    }
                } else {
#pragma unroll
                    for (int r = 0; r < 4; r++) {
                        long row = m0e + wm * 128 + mi * 16 + quad * 4 + r;
                        float v = acc[mi][ni][r] + bb[ni];
                        ((u16*)o0)[row * NN + col] = f2bfu(MODE == 1 ? geluf(v) : v);
                    }
                }
                acc[mi][ni] = (f32x4){0.f, 0.f, 0.f, 0.f};
            }
        }
    };

    // prologue: A(0),B(0) staged; B(1) in flight
    stA(0, 0); stA(0, 1); stA(0, 2); stA(0, 3);
    stB(0, 0); stB(0, 1); stB(0, 2); stB(0, 3);
    stB(1, 0); stB(1, 1); stB(1, 2); stB(1, 3);
    asm volatile("s_waitcnt vmcnt(4)" ::: "memory");
    __builtin_amdgcn_s_barrier();

    bf16x8 af[4][2];  // MH=0 fragments
    bf16x8 ag[4][2];  // MH=1 fragments (separate: written ph1 while af live)
    bf16x8 bfr[2][2][2];

#pragma unroll 2
    for (int s = 0; s < TOT; ++s) {
        const u16* sa = &sA2[s & 1][0];
        const u16* sb = &sB2[s & 1][0];
        // ph0: R0 = {af0, bf0}; R1 = {bf1}; stage A(s+1) halves 0-1; q(0,0) waits R0
        ld_a<0>(af, sa, wm, col16, cp0, cp1);
        ld_b<0>(bfr, sb, wn, col16, cp0, cp1);
        __builtin_amdgcn_sched_barrier(0);
        ld_b<1>(bfr, sb, wn, col16, cp0, cp1);
        __builtin_amdgcn_sched_barrier(0);
        stA(s + 1, 0);
        stA(s + 1, 1);
        PH_CNT(0, 0, af, 4)
        __builtin_amdgcn_s_barrier();
        // ph1: R2 = {ag}; stage A(s+1) halves 2-3; q(0,1) waits R1
        ld_a<1>(ag, sa, wm, col16, cp0, cp1);
        __builtin_amdgcn_sched_barrier(0);
        stA(s + 1, 2);
        stA(s + 1, 3);
        PH_CNT(0, 1, af, 8)
        __builtin_amdgcn_s_barrier();
        // ph2: stage B(s+2) halves 0-1; q(1,0) waits R2
        stB(s + 2, 0);
        stB(s + 2, 1);
        PH_CNT(1, 0, ag, 0)
        __builtin_amdgcn_s_barrier();
        // ph3: stage B(s+2) halves 2-3; q(1,1) (all fragments already waited)
        stB(s + 2, 2);
        stB(s + 2, 3);
        PH_CNT(1, 1, ag, 0)
        if (s + 2 < TOT)
            asm volatile("s_waitcnt vmcnt(4)" ::: "memory");  // counted: B(s+2) in flight
        else if (s + 1 < TOT)
            asm volatile("s_waitcnt vmcnt(0)" ::: "memory");  // tail drain
        __builtin_amdgcn_s_barrier();
        if ((s & (NT - 1)) == NT - 1) epi(s / NT);
    }
}

// ---------------- wave-level LN helpers (one wave per row of 512) ----------------
__device__ __forceinline__ float wredsum(float v) {
#pragma unroll
    for (int off = 1; off < 64; off <<= 1) v += __shfl_xor(v, off);
    return v;
}
__device__ __forceinline__ void ln8(float v[8]) {
    float s = 0.f;
#pragma unroll
    for (int j = 0; j < 8; j++) s += v[j];
    s = wredsum(s);
    float m = s * (1.0f / 512.0f);
    float q = 0.f;
#pragma unroll
    for (int j = 0; j < 8; j++) {
        v[j] -= m;
        q += v[j] * v[j];
    }
    q = wredsum(q);
    float inv = rsqrtf(q * (1.0f / 512.0f) + 1e-12f);
#pragma unroll
    for (int j = 0; j < 8; j++) v[j] *= inv;
}

// ---------------- embed: concat(question, LN(videoproj)) + pos + mod, LN ---------------
__global__ __launch_bounds__(256) void embed_kernel(
    const void* __restrict__ question, const void* __restrict__ pos, const void* __restrict__ mod,
    const u16* __restrict__ tmp, const void* __restrict__ nvg, const void* __restrict__ nvb,
    const void* __restrict__ eg, const void* __restrict__ eb, u16* __restrict__ x,
    const int* __restrict__ flag) {
    const int isbf = *flag;
    const int wave = threadIdx.x >> 6, lane = threadIdx.x & 63;
    const long row = (long)blockIdx.x * 4 + wave;
    const int b = (int)(row >> 9), s = (int)(row & 511);
    const int d0 = lane * 4, d1 = 256 + lane * 4;
    float v[8];
    if (s < Qq) {
        long base = ((long)b * Qq + s) * Dd;
#pragma unroll
        for (int j = 0; j < 4; j++) {
            v[j] = ldx(question, base + d0 + j, isbf);
            v[4 + j] = ldx(question, base + d1 + j, isbf);
        }
    } else {
        const u16* tr = tmp + ((long)b * Tt + (s - Qq)) * Dd;
        u16x4 f0 = *(const u16x4*)(tr + d0);
        u16x4 f1 = *(const u16x4*)(tr + d1);
#pragma unroll
        for (int j = 0; j < 4; j++) {
            v[j] = bf2f(f0[j]);
            v[4 + j] = bf2f(f1[j]);
        }
        ln8(v);
#pragma unroll
        for (int j = 0; j < 4; j++) {
            v[j] = v[j] * ldx(nvg, d0 + j, isbf) + ldx(nvb, d0 + j, isbf);
            v[4 + j] = v[4 + j] * ldx(nvg, d1 + j, isbf) + ldx(nvb, d1 + j, isbf);
        }
    }
    const int mid = (s < Qq) ? 0 : 1;
#pragma unroll
    for (int j = 0; j < 4; j++) {
        v[j] += ldx(pos, (long)s * Dd + d0 + j, isbf) + ldx(mod, (long)mid * Dd + d0 + j, isbf);
        v[4 + j] += ldx(pos, (long)s * Dd + d1 + j, isbf) + ldx(mod, (long)mid * Dd + d1 + j, isbf);
    }
    ln8(v);
#pragma unroll
    for (int j = 0; j < 4; j++) {
        x[row * Dd + d0 + j] = f2bfu(v[j] * ldx(eg, d0 + j, isbf) + ldx(eb, d0 + j, isbf));
        x[row * Dd + d1 + j] = f2bfu(v[4 + j] * ldx(eg, d1 + j, isbf) + ldx(eb, d1 + j, isbf));
    }
}

// ---------------- add residual + LN (tmp is bf16) ----------------
__global__ __launch_bounds__(256) void add_ln_kernel(const u16* __restrict__ tmp,
                                                     const u16* __restrict__ xin,
                                                     const void* __restrict__ g,
                                                     const void* __restrict__ bta, long goff,
                                                     void* __restrict__ dst, int dst_is_final,
                                                     const int* __restrict__ flag) {
    const int isbf = *flag;
    const int wave = threadIdx.x >> 6, lane = threadIdx.x & 63;
    const long row = (long)blockIdx.x * 4 + wave;
    const int d0 = lane * 4, d1 = 256 + lane * 4;
    u16x4 t0 = *(const u16x4*)(tmp + row * Dd + d0);
    u16x4 t1 = *(const u16x4*)(tmp + row * Dd + d1);
    u16x4 x0 = *(const u16x4*)(xin + row * Dd + d0);
    u16x4 x1 = *(const u16x4*)(xin + row * Dd + d1);
    float v[8];
#pragma unroll
    for (int j = 0; j < 4; j++) {
        v[j] = bf2f(t0[j]) + bf2f(x0[j]);
        v[4 + j] = bf2f(t1[j]) + bf2f(x1[j]);
    }
    ln8(v);
#pragma unroll
    for (int j = 0; j < 8; j++) {
        int d = (j < 4) ? d0 + j : d1 + j - 4;
        v[j] = v[j] * ldx(g, goff + d, isbf) + ldx(bta, goff + d, isbf);
    }
    if (dst_is_final && !isbf) {
#pragma unroll
        for (int j = 0; j < 4; j++) {
            ((float*)dst)[row * Dd + d0 + j] = v[j];
            ((float*)dst)[row * Dd + d1 + j] = v[4 + j];
        }
    } else {
#pragma unroll
        for (int j = 0; j < 4; j++) {
            ((u16*)dst)[row * Dd + d0 + j] = f2bfu(v[j]);
            ((u16*)dst)[row * Dd + d1 + j] = f2bfu(v[4 + j]);
        }
    }
}

// ---------------- flash attention v3 (unchanged, proven) ----------------
__global__ __launch_bounds__(256) void flash_kernel(const u16* __restrict__ q,
                                                    const u16* __restrict__ k,
                                                    const u16* __restrict__ vT,
                                                    const int* __restrict__ mask,
                                                    u16* __restrict__ ctx) {
    __shared__ __align__(16) u16 sK[64 * 64];
    __shared__ __align__(16) u16 sV[64 * 64];
    __shared__ __align__(16) u16 pbuf[4][16 * 72];
    __shared__ float smaskf[Ss];

    const int tid = threadIdx.x;
    const int lane = tid & 63, wave = tid >> 6;
    const int col16 = lane & 15, quad = lane >> 4;
    const int bid = blockIdx.x;
    const int qt = bid >> 9;
    const int bh = bid & 511;
    const int b = bh & 63, h = bh >> 6;
    const long bhl = (long)b * Hh + h;
    const u16* qp = q + bhl * Ss * DHh;
    const u16* kp = k + bhl * Ss * DHh;
    const u16* vp = vT + bhl * DHh * Ss;

    smaskf[tid] = mask[b * Ss + tid] ? 0.f : -1e30f;
    smaskf[tid + 256] = mask[b * Ss + tid + 256] ? 0.f : -1e30f;

    const int qbase = qt * 128 + wave * 32;
    bf16x8 aq[2][2];
#pragma unroll
    for (int t = 0; t < 2; t++) {
        aq[t][0] = *(const bf16x8*)&qp[(qbase + t * 16 + col16) * 64 + quad * 8];
        aq[t][1] = *(const bf16x8*)&qp[(qbase + t * 16 + col16) * 64 + 32 + quad * 8];
    }

    bf16x8 vone;
#pragma unroll
    for (int j = 0; j < 8; j++) vone[j] = (__bf16)1.0f;

    float mr[2][4];
    f32x4 acc[2][4], accl[2];
#pragma unroll
    for (int t = 0; t < 2; t++) {
        accl[t] = (f32x4){0.f, 0.f, 0.f, 0.f};
#pragma unroll
        for (int r = 0; r < 4; r++) mr[t][r] = -1e30f;
#pragma unroll
        for (int dt = 0; dt < 4; dt++) acc[t][dt] = (f32x4){0.f, 0.f, 0.f, 0.f};
    }

    for (int c0 = 0; c0 < Ss; c0 += 64) {
        __syncthreads();
#pragma unroll
        for (int i = 0; i < 2; i++) {
            int ci = i * 256 + tid;
            int row = ci >> 3, sl = ci & 7;
            int sg = sl ^ (row & 7);  // xor swizzle on the GLOBAL side
            int lbase = (i * 256 + wave * 64) * 8;
            gload16(&kp[(c0 + row) * 64 + sg * 8], &sK[lbase]);
            gload16(&vp[row * 512 + c0 + sg * 8], &sV[lbase]);
        }
        __syncthreads();

        bf16x8 bk[4][2];
#pragma unroll
        for (int nt = 0; nt < 4; nt++) {
            int r = nt * 16 + col16;
            bk[nt][0] = *(const bf16x8*)&sK[(r * 8 + (quad ^ (r & 7))) * 8];
            bk[nt][1] = *(const bf16x8*)&sK[(r * 8 + ((4 + quad) ^ (r & 7))) * 8];
        }

#pragma unroll
        for (int t = 0; t < 2; t++) {
            f32x4 sc[4];
#pragma unroll
            for (int nt = 0; nt < 4; nt++) {
                f32x4 z = (f32x4){0.f, 0.f, 0.f, 0.f};
                z = MFMA16(aq[t][0], bk[nt][0], z);
                z = MFMA16(aq[t][1], bk[nt][1], z);
                float mf = smaskf[c0 + nt * 16 + col16];
#pragma unroll
                for (int r = 0; r < 4; r++) z[r] += mf;
                sc[nt] = z;
            }
            float alpha[4];
#pragma unroll
            for (int r = 0; r < 4; r++) {
                float cm = fmaxf(fmaxf(sc[0][r], sc[1][r]), fmaxf(sc[2][r], sc[3][r]));
#pragma unroll
                for (int off = 1; off < 16; off <<= 1) cm = fmaxf(cm, __shfl_xor(cm, off));
                float mn = fmaxf(mr[t][r], cm);
                alpha[r] = __expf(mr[t][r] - mn);
                mr[t][r] = mn;
#pragma unroll
                for (int nt = 0; nt < 4; nt++)
                    pbuf[wave][(quad * 4 + r) * 72 + nt * 16 + col16] =
                        f2bfu(__expf(sc[nt][r] - mn));
            }
#pragma unroll
            for (int dt = 0; dt < 4; dt++) {
#pragma unroll
                for (int r = 0; r < 4; r++) acc[t][dt][r] *= alpha[r];
            }
#pragma unroll
            for (int r = 0; r < 4; r++) accl[t][r] *= alpha[r];
#pragma unroll
            for (int hf = 0; hf < 2; hf++) {
                bf16x8 ap = *(const bf16x8*)&pbuf[wave][col16 * 72 + hf * 32 + quad * 8];
#pragma unroll
                for (int dt = 0; dt < 4; dt++) {
                    int d = dt * 16 + col16;
                    bf16x8 bv = *(const bf16x8*)&sV[(d * 8 + ((hf * 4 + quad) ^ (d & 7))) * 8];
                    acc[t][dt] = MFMA16(ap, bv, acc[t][dt]);
                }
                accl[t] = MFMA16(ap, vone, accl[t]);
            }
        }
    }
#pragma unroll
    for (int t = 0; t < 2; t++)
#pragma unroll
        for (int dt = 0; dt < 4; dt++) {
#pragma unroll
            for (int r = 0; r < 4; r++) {
                float v = acc[t][dt][r] / accl[t][r];
                int sq = qbase + t * 16 + quad * 4 + r;
                int d = h * 64 + dt * 16 + col16;
                ctx[((long)b * Ss + sq) * Dd + d] = f2bfu(v);
            }
        }
}

// ---------------- host ----------------
extern "C" void kernel_launch(void* const* d_in, const int* in_sizes, int n_in, void* d_out,
                              int out_size, void* d_ws, size_t ws_size, hipStream_t stream) {
    const void* video = d_in[0];
    const void* question = d_in[1];
    const int* mask = (const int*)d_in[2];
    const void* pos_emb = d_in[3];
    const void* mod_emb = d_in[4];
    const void* Wv = d_in[5];
    const void* bv = d_in[6];
    const void* nv_g = d_in[7];
    const void* nv_b = d_in[8];
    const void* emb_g = d_in[9];
    const void* emb_b = d_in[10];
    const void* Wq = d_in[11];
    const void* bq = d_in[12];
    const void* Wk = d_in[13];
    const void* bk = d_in[14];
    const void* Wva = d_in[15];
    const void* bva = d_in[16];
    const void* Wo = d_in[17];
    const void* bo = d_in[18];
    const void* ln1_g = d_in[19];
    const void* ln1_b = d_in[20];
    const void* W1 = d_in[21];
    const void* b1 = d_in[22];
    const void* W2 = d_in[23];
    const void* b2 = d_in[24];
    const void* ln2_g = d_in[25];
    const void* ln2_b = d_in[26];

    char* wsb = (char*)d_ws;
    size_t off = 0;
    auto alloc = [&](size_t bytes) -> void* {
        void* p = (void*)(wsb + off);
        off += (bytes + 4095) & ~((size_t)4095);
        return p;
    };
    int* flag = (int*)alloc(16);
    u16* WvT = (u16*)alloc((size_t)Dd * FDd * 2);
    u16 *WqkvT[NL], *WoT[NL], *W1T[NL], *W2T[NL];
    for (int i = 0; i < NL; i++) {
        WqkvT[i] = (u16*)alloc((size_t)3 * Dd * Dd * 2);
        WoT[i] = (u16*)alloc((size_t)Dd * Dd * 2);
        W1T[i] = (u16*)alloc((size_t)FFf * Dd * 2);
        W2T[i] = (u16*)alloc((size_t)Dd * FFf * 2);
    }
    u16* x = (u16*)alloc((size_t)Bb * Ss * Dd * 2);    // 32 MB residual stream (bf16)
    u16* tmp = (u16*)alloc((size_t)Bb * Ss * Dd * 2);  // 32 MB bf16 GEMM out
    char* uni = (char*)alloc((size_t)134217728);       // union region (lifetimes disjoint)
    u16* videob = (u16*)uni;                           // video bf16   [dead after video GEMM]
    u16* qb = (u16*)uni;                               // q            [B,H,S,DH]
    u16* kb = (u16*)(uni + 33554432);                  // k            [B,H,S,DH]
    u16* vtb = (u16*)(uni + 67108864);                 // v^T          [B,H,DH,S]
    u16* ctxb = (u16*)(uni + 100663296);               // ctx          [B,S,D]
    u16* hb = (u16*)uni;                               // FFN hidden   [B,S,FF] (128 MB)

    dim3 tb(32, 8);

    probe_kernel<<<dim3(1), dim3(64), 0, stream>>>(pos_emb, flag);
    convert_kernel<<<dim3(8192), dim3(256), 0, stream>>>(video, videob, (long)Bb * Tt * FDd, flag);

    transpose_kernel<<<dim3(Dd / 32, FDd / 32), tb, 0, stream>>>(Wv, WvT, FDd, Dd, 0L, flag);
    for (int i = 0; i < NL; i++) {
        transpose4_kernel<<<dim3(Dd / 32, Dd / 32, 4), tb, 0, stream>>>(
            Wq, Wk, Wva, Wo, WqkvT[i], WqkvT[i] + (size_t)Dd * Dd,
            WqkvT[i] + (size_t)2 * Dd * Dd, WoT[i], (long)i * Dd * Dd, flag);
        transpose_kernel<<<dim3(FFf / 32, Dd / 32), tb, 0, stream>>>(W1, W1T[i], Dd, FFf,
                                                                     (long)i * Dd * FFf, flag);
        transpose_kernel<<<dim3(Dd / 32, FFf / 32), tb, 0, stream>>>(W2, W2T[i], FFf, Dd,
                                                                     (long)i * FFf * Dd, flag);
    }

    // video projection: [28672,1024] @ [1024,512] -> tmp bf16 (A = video directly if bf16)
    gemm256<0, FDd, Dd, 1><<<dim3(224), dim3(512), 0, stream>>>(
        videob, video, WvT, bv, nullptr, nullptr, 0L, tmp, nullptr, nullptr, Bb * Tt, flag);
    embed_kernel<<<dim3((Bb * Ss) / 4), dim3(256), 0, stream>>>(question, pos_emb, mod_emb, tmp,
                                                                nv_g, nv_b, emb_g, emb_b, x, flag);

    for (int i = 0; i < NL; i++) {
        gemm256<2, Dd, 1536, 1><<<dim3(768), dim3(512), 0, stream>>>(
            x, nullptr, WqkvT[i], bq, bk, bva, (long)i * Dd, qb, kb, vtb, Bb * Ss, flag);
        flash_kernel<<<dim3(2048), dim3(256), 0, stream>>>(qb, kb, vtb, mask, ctxb);
        gemm256<0, Dd, Dd, 1><<<dim3(256), dim3(512), 0, stream>>>(
            ctxb, nullptr, WoT[i], bo, nullptr, nullptr, (long)i * Dd, tmp, nullptr, nullptr,
            Bb * Ss, flag);
        add_ln_kernel<<<dim3((Bb * Ss) / 4), dim3(256), 0, stream>>>(tmp, x, ln1_g, ln1_b,
                                                                     (long)i * Dd, x, 0, flag);
        gemm256<1, Dd, FFf, 4><<<dim3(256), dim3(512), 0, stream>>>(
            x, nullptr, W1T[i], b1, nullptr, nullptr, (long)i * FFf, hb, nullptr, nullptr,
            Bb * Ss, flag);
        gemm256<0, FFf, Dd, 1><<<dim3(256), dim3(512), 0, stream>>>(
            hb, nullptr, W2T[i], b2, nullptr, nullptr, (long)i * Dd, tmp, nullptr, nullptr,
            Bb * Ss, flag);
        void* dst = (i == NL - 1) ? d_out : (void*)x;
        add_ln_kernel<<<dim3((Bb * Ss) / 4), dim3(256), 0, stream>>>(
            tmp, x, ln2_g, ln2_b, (long)i * Dd, dst, (i == NL - 1) ? 1 : 0, flag);
    }
    (void)in_sizes; (void)n_in; (void)out_size; (void)ws_size;
}

// Round 5
// 1232.022 us; speedup vs baseline: 1.3075x; 1.3075x over previous
//
#include <hip/hip_runtime.h>
#include <hip/hip_bf16.h>
#include <stdint.h>

// Problem constants
#define Bb 64
#define Qq 64
#define Tt 448
#define Dd 512
#define FDd 1024
#define Hh 8
#define NL 2
#define FFf 2048
#define Ss 512
#define DHh 64

typedef unsigned short u16;
typedef __bf16 bf16x8 __attribute__((ext_vector_type(8)));
typedef float f32x4 __attribute__((ext_vector_type(4)));
typedef u16 u16x4 __attribute__((ext_vector_type(4)));

__device__ __forceinline__ float bf2f(u16 u) { return __uint_as_float(((uint32_t)u) << 16); }
__device__ __forceinline__ u16 f2bfu(float f) {
    __bf16 h = (__bf16)f;
    return __builtin_bit_cast(unsigned short, h);
}
// Dual-mode load: input tensors may be bf16 (flag=1) or fp32 (flag=0)
__device__ __forceinline__ float ldx(const void* p, long i, int isbf) {
    return isbf ? bf2f(((const u16*)p)[i]) : ((const float*)p)[i];
}
// fast gelu: x*sigmoid(2c*x*(1+0.044715x^2)), c=0.79788456 (tanh-form, |err|<1e-3)
__device__ __forceinline__ float geluf(float v) {
    float u = v * (1.0f + 0.044715f * v * v) * -1.5957691216057308f;
    return v / (1.0f + __expf(u));
}
// async global->LDS, 16B per lane; lds ptr must be wave-uniform base (HW adds lane*16)
__device__ __forceinline__ void gload16(const void* g, void* l) {
    __builtin_amdgcn_global_load_lds((const __attribute__((address_space(1))) void*)g,
                                     (__attribute__((address_space(3))) void*)l, 16, 0, 0);
}
#define MFMA16(a, b, c) __builtin_amdgcn_mfma_f32_16x16x32_bf16(a, b, c, 0, 0, 0)

// ---------------- dtype probe ----------------
__global__ void probe_kernel(const void* pos_emb, int* flag) {
    if (threadIdx.x == 0) {
        uint32_t w = *(const uint32_t*)pos_emb;
        *flag = (w == 0x3F800000u) ? 1 : 0;
    }
}

// ---------------- convert (video -> canonical bf16; no-op when already bf16) -----------
__global__ void convert_kernel(const void* __restrict__ src, u16* __restrict__ dst, long n,
                               const int* __restrict__ flag) {
    const int isbf = *flag;
    if (isbf) return;  // video GEMM reads the original bf16 tensor directly
    long i = (long)blockIdx.x * blockDim.x + threadIdx.x;
    long stride = (long)gridDim.x * blockDim.x;
    for (; i < n; i += stride) {
        dst[i] = f2bfu(((const float*)src)[i]);
    }
}

// ---------------- dual-mode weight transpose: W[R,C] -> Wt[C,R] (bf16 out) -------------
__global__ void transpose_kernel(const void* __restrict__ src, u16* __restrict__ dst,
                                 int R, int C, long elem_off, const int* __restrict__ flag) {
    __shared__ u16 tile[32][33];
    const int isbf = *flag;
    const int c0 = blockIdx.x * 32, r0 = blockIdx.y * 32;
    const int tx = threadIdx.x, ty = threadIdx.y;
#pragma unroll
    for (int i = 0; i < 32; i += 8) {
        long idx = elem_off + (long)(r0 + ty + i) * C + (c0 + tx);
        tile[ty + i][tx] = isbf ? ((const u16*)src)[idx] : f2bfu(((const float*)src)[idx]);
    }
    __syncthreads();
#pragma unroll
    for (int i = 0; i < 32; i += 8) {
        dst[(long)(c0 + ty + i) * R + (r0 + tx)] = tile[tx][ty + i];
    }
}

// ---- batched 512x512 transpose: z selects {Wq,Wk,Wva,Wo} ------------------------------
__global__ void transpose4_kernel(const void* __restrict__ s0, const void* __restrict__ s1,
                                  const void* __restrict__ s2, const void* __restrict__ s3,
                                  u16* __restrict__ d0p, u16* __restrict__ d1p,
                                  u16* __restrict__ d2p, u16* __restrict__ d3p, long elem_off,
                                  const int* __restrict__ flag) {
    __shared__ u16 tile[32][33];
    const int isbf = *flag;
    const int z = blockIdx.z;
    const void* src = (z == 0) ? s0 : (z == 1) ? s1 : (z == 2) ? s2 : s3;
    u16* dst = (z == 0) ? d0p : (z == 1) ? d1p : (z == 2) ? d2p : d3p;
    const int c0 = blockIdx.x * 32, r0 = blockIdx.y * 32;
    const int tx = threadIdx.x, ty = threadIdx.y;
#pragma unroll
    for (int i = 0; i < 32; i += 8) {
        long idx = elem_off + (long)(r0 + ty + i) * Dd + (c0 + tx);
        tile[ty + i][tx] = isbf ? ((const u16*)src)[idx] : f2bfu(((const float*)src)[idx]);
    }
    __syncthreads();
#pragma unroll
    for (int i = 0; i < 32; i += 8) {
        dst[(long)(c0 + ty + i) * Dd + (r0 + tx)] = tile[tx][ty + i];
    }
}

// ============ 256x256 GEMM, BK=32, 64 KiB LDS (2 blocks/CU), 2 barriers/kt =============
// C[M,N] = A[M,K] @ Bt[N,K]^T + bias. MODE 0: bf16 out; MODE 1: + gelu; MODE 2: QKV
// scatter. 512 thr = 8 waves (2 wm x 4 wn); per-wave C = 128x64 = acc[8][4] f32x4.
// LDS: sA2/sB2[2][256 rows x 32 k] double-buffered by kt parity = 64 KiB total ->
// 2 blocks/CU; a second block's MFMA covers this block's read-epoch + barrier stalls.
// Pair-row LDS layout (flash-kernel-proven, 2-way banks = free): pair p = row>>1 holds
// 8x16B slots; slot s stores global (row-parity,chunk) gidx = s ^ (p&7).
// Per kt (K=32): ph0 {issue 12 ds_reads (af,bfr | ag); stage A(s+1); lgkm(4); 16 MFMA;
// BAR} ph1 {stage B(s+2) [safe: all bfr reads retired via MFMA dep before BAR];
// lgkm(0); 16 MFMA; vmcnt(2) counted -- B(s+2) stays in flight; BAR}.
// Staging-hazard safety rides on MFMA data-deps (compiler waits) before each barrier.
// XCD-chunked remap (T1): xcd=bid&7 owns contiguous m-chunk; n iterates fastest (A-panel
// L2 reuse across the nbn blocks of one XCD; proven FETCH 135->49 MB on W1).
__device__ __forceinline__ int lds_off(int rr, int quad) {
    return (rr >> 1) * 64 + (((((rr & 1) << 2) | quad) ^ ((rr >> 1) & 7)) * 8);
}

template <int MODE, int KK, int NN>
__global__ __launch_bounds__(512) void gemm256(
    const u16* __restrict__ A, const void* __restrict__ Araw, const u16* __restrict__ Bt,
    const void* __restrict__ b0, const void* __restrict__ b1, const void* __restrict__ b2,
    long boff, void* __restrict__ o0, void* __restrict__ o1, void* __restrict__ o2, int M,
    const int* __restrict__ flag) {
    constexpr int TOT = KK / 32;  // K-steps
    constexpr int nbn = NN >> 8;
    __shared__ __align__(16) u16 sA2[2][8192];
    __shared__ __align__(16) u16 sB2[2][8192];
    const int tid = threadIdx.x;
    const int lane = tid & 63, wave = tid >> 6;
    const int wm = wave >> 2, wn = wave & 3;
    const int col16 = lane & 15, quad = lane >> 4;
    const int isbf = *flag;
    const u16* Ap = (Araw && isbf) ? (const u16*)Araw : A;

    // XCD-chunked remap: m-chunk per XCD, n fastest within XCD
    const int bid = blockIdx.x;
    const int xcd = bid & 7;
    const int loc = bid >> 3;
    const int nbm = M >> 8;
    const int chunk = nbm >> 3;
    const int mloc = loc / nbn;
    const int nloc = loc - mloc * nbn;
    const long m0 = (long)(xcd * chunk + mloc) << 8;
    const long n0 = (long)nloc << 8;

    // staging: thread -> pair p = tid>>3, slot = tid&7, global gidx = slot ^ (p&7);
    // global row = 2p + (gidx>>2), 16B chunk = gidx&3. Per call: 128 rows (q*128 offset).
    const int gidx = (tid & 7) ^ ((tid >> 3) & 7);
    const int grow = 2 * (tid >> 3) + (gidx >> 2);
    const u16* agbase = Ap + (m0 + grow) * KK + (gidx & 3) * 8;
    const u16* bgbase = Bt + (n0 + grow) * KK + (gidx & 3) * 8;

    auto stA = [&](int s2, int q) {
        if (s2 < TOT)
            gload16(agbase + (long)q * (128LL * KK) + (long)s2 * 32,
                    &sA2[s2 & 1][q * 4096 + wave * 512]);
    };
    auto stB = [&](int s2, int q) {
        if (s2 < TOT)
            gload16(bgbase + (long)q * (128LL * KK) + (long)s2 * 32,
                    &sB2[s2 & 1][q * 4096 + wave * 512]);
    };

    f32x4 acc[8][4];
#pragma unroll
    for (int i = 0; i < 8; i++)
#pragma unroll
        for (int j = 0; j < 4; j++) acc[i][j] = (f32x4){0.f, 0.f, 0.f, 0.f};

    // prologue: A(0),B(0) staged; B(1) in flight (counted)
    stA(0, 0); stA(0, 1);
    stB(0, 0); stB(0, 1);
    stB(1, 0); stB(1, 1);
    asm volatile("s_waitcnt vmcnt(2)" ::: "memory");
    __builtin_amdgcn_s_barrier();

    bf16x8 af[4], ag[4], bfr[4];

#pragma unroll 2
    for (int s = 0; s < TOT; ++s) {
        const u16* sa = &sA2[s & 1][0];
        const u16* sb = &sB2[s & 1][0];
        // ph0: issue reads (af+bfr first, then ag), stage A(s+1)
#pragma unroll
        for (int mi = 0; mi < 4; mi++)
            af[mi] = *(const bf16x8*)&sa[lds_off(wm * 128 + mi * 16 + col16, quad)];
#pragma unroll
        for (int ni = 0; ni < 4; ni++)
            bfr[ni] = *(const bf16x8*)&sb[lds_off(wn * 64 + ni * 16 + col16, quad)];
        __builtin_amdgcn_sched_barrier(0);
#pragma unroll
        for (int mi = 0; mi < 4; mi++)
            ag[mi] = *(const bf16x8*)&sa[lds_off(wm * 128 + 64 + mi * 16 + col16, quad)];
        __builtin_amdgcn_sched_barrier(0);
        stA(s + 1, 0);
        stA(s + 1, 1);
        __builtin_amdgcn_sched_barrier(0);
        asm volatile("s_waitcnt lgkmcnt(4)" ::: "memory");  // af+bfr retired (ag in flight)
        __builtin_amdgcn_sched_barrier(0);
        __builtin_amdgcn_s_setprio(1);
#pragma unroll
        for (int mi = 0; mi < 4; mi++)
#pragma unroll
            for (int ni = 0; ni < 4; ni++) acc[mi][ni] = MFMA16(af[mi], bfr[ni], acc[mi][ni]);
        __builtin_amdgcn_s_setprio(0);
        __builtin_amdgcn_sched_barrier(0);
        __builtin_amdgcn_s_barrier();  // all waves' bfr reads retired -> sB[s&1] free
        // ph1: stage B(s+2) into sB[s&1]; MFMA second m-half
        stB(s + 2, 0);
        stB(s + 2, 1);
        __builtin_amdgcn_sched_barrier(0);
        asm volatile("s_waitcnt lgkmcnt(0)" ::: "memory");  // ag retired
        __builtin_amdgcn_sched_barrier(0);
        __builtin_amdgcn_s_setprio(1);
#pragma unroll
        for (int mi = 0; mi < 4; mi++)
#pragma unroll
            for (int ni = 0; ni < 4; ni++)
                acc[4 + mi][ni] = MFMA16(ag[mi], bfr[ni], acc[4 + mi][ni]);
        __builtin_amdgcn_s_setprio(0);
        __builtin_amdgcn_sched_barrier(0);
        if (s + 2 < TOT)
            asm volatile("s_waitcnt vmcnt(2)" ::: "memory");  // A(s+1) landed; B(s+2) in flight
        else
            asm volatile("s_waitcnt vmcnt(0)" ::: "memory");  // tail drain
        __builtin_amdgcn_s_barrier();  // buffers for kt s+1 ready for all waves
    }

    // ---------------- epilogue (post-loop; registers stay at loop level) ----------------
    if constexpr (MODE == 2) {
        const int region = (int)(n0 >> 9);  // 0=q, 1=k, 2=v (block-uniform; NN=1536)
        const void* bias = (region == 0) ? b0 : (region == 1) ? b1 : b2;
        float bb[4];
#pragma unroll
        for (int ni = 0; ni < 4; ni++) {
            long col = n0 + wn * 64 + ni * 16 + col16;
            bb[ni] = ldx(bias, boff + (col & 511), isbf);
        }
#pragma unroll
        for (int mi = 0; mi < 8; mi++) {
#pragma unroll
            for (int ni = 0; ni < 4; ni++) {
                long col = n0 + wn * 64 + ni * 16 + col16;
                long cc = col & 511;
                long h = cc >> 6, dh = cc & 63;
                long row0 = m0 + wm * 128 + mi * 16 + quad * 4;
                long b = row0 >> 9, s0 = row0 & 511;
                if (region == 0) {
#pragma unroll
                    for (int r = 0; r < 4; r++)
                        ((u16*)o0)[(((b * 8 + h) * 512) + s0 + r) * 64 + dh] =
                            f2bfu((acc[mi][ni][r] + bb[ni]) * 0.125f);
                } else if (region == 1) {
#pragma unroll
                    for (int r = 0; r < 4; r++)
                        ((u16*)o1)[(((b * 8 + h) * 512) + s0 + r) * 64 + dh] =
                            f2bfu(acc[mi][ni][r] + bb[ni]);
                } else {  // v^T: 4 consecutive s for fixed dh -> one 8B store
                    u16x4 pk;
#pragma unroll
                    for (int r = 0; r < 4; r++) pk[r] = f2bfu(acc[mi][ni][r] + bb[ni]);
                    *(u16x4*)&((u16*)o2)[(((b * 8 + h) * 64) + dh) * 512 + s0] = pk;
                }
            }
        }
    } else {
        float bb[4];
#pragma unroll
        for (int ni = 0; ni < 4; ni++)
            bb[ni] = ldx(b0, boff + n0 + wn * 64 + ni * 16 + col16, isbf);
#pragma unroll
        for (int mi = 0; mi < 8; mi++) {
#pragma unroll
            for (int ni = 0; ni < 4; ni++) {
                long col = n0 + wn * 64 + ni * 16 + col16;
#pragma unroll
                for (int r = 0; r < 4; r++) {
                    long row = m0 + wm * 128 + mi * 16 + quad * 4 + r;
                    float v = acc[mi][ni][r] + bb[ni];
                    ((u16*)o0)[row * NN + col] = f2bfu(MODE == 1 ? geluf(v) : v);
                }
            }
        }
    }
}

// ---------------- wave-level LN helpers (one wave per row of 512) ----------------
__device__ __forceinline__ float wredsum(float v) {
#pragma unroll
    for (int off = 1; off < 64; off <<= 1) v += __shfl_xor(v, off);
    return v;
}
__device__ __forceinline__ void ln8(float v[8]) {
    float s = 0.f;
#pragma unroll
    for (int j = 0; j < 8; j++) s += v[j];
    s = wredsum(s);
    float m = s * (1.0f / 512.0f);
    float q = 0.f;
#pragma unroll
    for (int j = 0; j < 8; j++) {
        v[j] -= m;
        q += v[j] * v[j];
    }
    q = wredsum(q);
    float inv = rsqrtf(q * (1.0f / 512.0f) + 1e-12f);
#pragma unroll
    for (int j = 0; j < 8; j++) v[j] *= inv;
}

// ---------------- embed: concat(question, LN(videoproj)) + pos + mod, LN ---------------
__global__ __launch_bounds__(256) void embed_kernel(
    const void* __restrict__ question, const void* __restrict__ pos, const void* __restrict__ mod,
    const u16* __restrict__ tmp, const void* __restrict__ nvg, const void* __restrict__ nvb,
    const void* __restrict__ eg, const void* __restrict__ eb, u16* __restrict__ x,
    const int* __restrict__ flag) {
    const int isbf = *flag;
    const int wave = threadIdx.x >> 6, lane = threadIdx.x & 63;
    const long row = (long)blockIdx.x * 4 + wave;
    const int b = (int)(row >> 9), s = (int)(row & 511);
    const int d0 = lane * 4, d1 = 256 + lane * 4;
    float v[8];
    if (s < Qq) {
        long base = ((long)b * Qq + s) * Dd;
#pragma unroll
        for (int j = 0; j < 4; j++) {
            v[j] = ldx(question, base + d0 + j, isbf);
            v[4 + j] = ldx(question, base + d1 + j, isbf);
        }
    } else {
        const u16* tr = tmp + ((long)b * Tt + (s - Qq)) * Dd;
        u16x4 f0 = *(const u16x4*)(tr + d0);
        u16x4 f1 = *(const u16x4*)(tr + d1);
#pragma unroll
        for (int j = 0; j < 4; j++) {
            v[j] = bf2f(f0[j]);
            v[4 + j] = bf2f(f1[j]);
        }
        ln8(v);
#pragma unroll
        for (int j = 0; j < 4; j++) {
            v[j] = v[j] * ldx(nvg, d0 + j, isbf) + ldx(nvb, d0 + j, isbf);
            v[4 + j] = v[4 + j] * ldx(nvg, d1 + j, isbf) + ldx(nvb, d1 + j, isbf);
        }
    }
    const int mid = (s < Qq) ? 0 : 1;
#pragma unroll
    for (int j = 0; j < 4; j++) {
        v[j] += ldx(pos, (long)s * Dd + d0 + j, isbf) + ldx(mod, (long)mid * Dd + d0 + j, isbf);
        v[4 + j] += ldx(pos, (long)s * Dd + d1 + j, isbf) + ldx(mod, (long)mid * Dd + d1 + j, isbf);
    }
    ln8(v);
#pragma unroll
    for (int j = 0; j < 4; j++) {
        x[row * Dd + d0 + j] = f2bfu(v[j] * ldx(eg, d0 + j, isbf) + ldx(eb, d0 + j, isbf));
        x[row * Dd + d1 + j] = f2bfu(v[4 + j] * ldx(eg, d1 + j, isbf) + ldx(eb, d1 + j, isbf));
    }
}

// ---------------- add residual + LN (tmp is bf16) ----------------
__global__ __launch_bounds__(256) void add_ln_kernel(const u16* __restrict__ tmp,
                                                     const u16* __restrict__ xin,
                                                     const void* __restrict__ g,
                                                     const void* __restrict__ bta, long goff,
                                                     void* __restrict__ dst, int dst_is_final,
                                                     const int* __restrict__ flag) {
    const int isbf = *flag;
    const int wave = threadIdx.x >> 6, lane = threadIdx.x & 63;
    const long row = (long)blockIdx.x * 4 + wave;
    const int d0 = lane * 4, d1 = 256 + lane * 4;
    u16x4 t0 = *(const u16x4*)(tmp + row * Dd + d0);
    u16x4 t1 = *(const u16x4*)(tmp + row * Dd + d1);
    u16x4 x0 = *(const u16x4*)(xin + row * Dd + d0);
    u16x4 x1 = *(const u16x4*)(xin + row * Dd + d1);
    float v[8];
#pragma unroll
    for (int j = 0; j < 4; j++) {
        v[j] = bf2f(t0[j]) + bf2f(x0[j]);
        v[4 + j] = bf2f(t1[j]) + bf2f(x1[j]);
    }
    ln8(v);
#pragma unroll
    for (int j = 0; j < 8; j++) {
        int d = (j < 4) ? d0 + j : d1 + j - 4;
        v[j] = v[j] * ldx(g, goff + d, isbf) + ldx(bta, goff + d, isbf);
    }
    if (dst_is_final && !isbf) {
#pragma unroll
        for (int j = 0; j < 4; j++) {
            ((float*)dst)[row * Dd + d0 + j] = v[j];
            ((float*)dst)[row * Dd + d1 + j] = v[4 + j];
        }
    } else {
#pragma unroll
        for (int j = 0; j < 4; j++) {
            ((u16*)dst)[row * Dd + d0 + j] = f2bfu(v[j]);
            ((u16*)dst)[row * Dd + d1 + j] = f2bfu(v[4 + j]);
        }
    }
}

// ---------------- flash attention v3 (unchanged, proven) ----------------
__global__ __launch_bounds__(256) void flash_kernel(const u16* __restrict__ q,
                                                    const u16* __restrict__ k,
                                                    const u16* __restrict__ vT,
                                                    const int* __restrict__ mask,
                                                    u16* __restrict__ ctx) {
    __shared__ __align__(16) u16 sK[64 * 64];
    __shared__ __align__(16) u16 sV[64 * 64];
    __shared__ __align__(16) u16 pbuf[4][16 * 72];
    __shared__ float smaskf[Ss];

    const int tid = threadIdx.x;
    const int lane = tid & 63, wave = tid >> 6;
    const int col16 = lane & 15, quad = lane >> 4;
    const int bid = blockIdx.x;
    const int qt = bid >> 9;
    const int bh = bid & 511;
    const int b = bh & 63, h = bh >> 6;
    const long bhl = (long)b * Hh + h;
    const u16* qp = q + bhl * Ss * DHh;
    const u16* kp = k + bhl * Ss * DHh;
    const u16* vp = vT + bhl * DHh * Ss;

    smaskf[tid] = mask[b * Ss + tid] ? 0.f : -1e30f;
    smaskf[tid + 256] = mask[b * Ss + tid + 256] ? 0.f : -1e30f;

    const int qbase = qt * 128 + wave * 32;
    bf16x8 aq[2][2];
#pragma unroll
    for (int t = 0; t < 2; t++) {
        aq[t][0] = *(const bf16x8*)&qp[(qbase + t * 16 + col16) * 64 + quad * 8];
        aq[t][1] = *(const bf16x8*)&qp[(qbase + t * 16 + col16) * 64 + 32 + quad * 8];
    }

    bf16x8 vone;
#pragma unroll
    for (int j = 0; j < 8; j++) vone[j] = (__bf16)1.0f;

    float mr[2][4];
    f32x4 acc[2][4], accl[2];
#pragma unroll
    for (int t = 0; t < 2; t++) {
        accl[t] = (f32x4){0.f, 0.f, 0.f, 0.f};
#pragma unroll
        for (int r = 0; r < 4; r++) mr[t][r] = -1e30f;
#pragma unroll
        for (int dt = 0; dt < 4; dt++) acc[t][dt] = (f32x4){0.f, 0.f, 0.f, 0.f};
    }

    for (int c0 = 0; c0 < Ss; c0 += 64) {
        __syncthreads();
#pragma unroll
        for (int i = 0; i < 2; i++) {
            int ci = i * 256 + tid;
            int row = ci >> 3, sl = ci & 7;
            int sg = sl ^ (row & 7);  // xor swizzle on the GLOBAL side
            int lbase = (i * 256 + wave * 64) * 8;
            gload16(&kp[(c0 + row) * 64 + sg * 8], &sK[lbase]);
            gload16(&vp[row * 512 + c0 + sg * 8], &sV[lbase]);
        }
        __syncthreads();

        bf16x8 bk[4][2];
#pragma unroll
        for (int nt = 0; nt < 4; nt++) {
            int r = nt * 16 + col16;
            bk[nt][0] = *(const bf16x8*)&sK[(r * 8 + (quad ^ (r & 7))) * 8];
            bk[nt][1] = *(const bf16x8*)&sK[(r * 8 + ((4 + quad) ^ (r & 7))) * 8];
        }

#pragma unroll
        for (int t = 0; t < 2; t++) {
            f32x4 sc[4];
#pragma unroll
            for (int nt = 0; nt < 4; nt++) {
                f32x4 z = (f32x4){0.f, 0.f, 0.f, 0.f};
                z = MFMA16(aq[t][0], bk[nt][0], z);
                z = MFMA16(aq[t][1], bk[nt][1], z);
                float mf = smaskf[c0 + nt * 16 + col16];
#pragma unroll
                for (int r = 0; r < 4; r++) z[r] += mf;
                sc[nt] = z;
            }
            float alpha[4];
#pragma unroll
            for (int r = 0; r < 4; r++) {
                float cm = fmaxf(fmaxf(sc[0][r], sc[1][r]), fmaxf(sc[2][r], sc[3][r]));
#pragma unroll
                for (int off = 1; off < 16; off <<= 1) cm = fmaxf(cm, __shfl_xor(cm, off));
                float mn = fmaxf(mr[t][r], cm);
                alpha[r] = __expf(mr[t][r] - mn);
                mr[t][r] = mn;
#pragma unroll
                for (int nt = 0; nt < 4; nt++)
                    pbuf[wave][(quad * 4 + r) * 72 + nt * 16 + col16] =
                        f2bfu(__expf(sc[nt][r] - mn));
            }
#pragma unroll
            for (int dt = 0; dt < 4; dt++) {
#pragma unroll
                for (int r = 0; r < 4; r++) acc[t][dt][r] *= alpha[r];
            }
#pragma unroll
            for (int r = 0; r < 4; r++) accl[t][r] *= alpha[r];
#pragma unroll
            for (int hf = 0; hf < 2; hf++) {
                bf16x8 ap = *(const bf16x8*)&pbuf[wave][col16 * 72 + hf * 32 + quad * 8];
#pragma unroll
                for (int dt = 0; dt < 4; dt++) {
                    int d = dt * 16 + col16;
                    bf16x8 bv = *(const bf16x8*)&sV[(d * 8 + ((hf * 4 + quad) ^ (d & 7))) * 8];
                    acc[t][dt] = MFMA16(ap, bv, acc[t][dt]);
                }
                accl[t] = MFMA16(ap, vone, accl[t]);
            }
        }
    }
#pragma unroll
    for (int t = 0; t < 2; t++)
#pragma unroll
        for (int dt = 0; dt < 4; dt++) {
#pragma unroll
            for (int r = 0; r < 4; r++) {
                float v = acc[t][dt][r] / accl[t][r];
                int sq = qbase + t * 16 + quad * 4 + r;
                int d = h * 64 + dt * 16 + col16;
                ctx[((long)b * Ss + sq) * Dd + d] = f2bfu(v);
            }
        }
}

// ---------------- host ----------------
extern "C" void kernel_launch(void* const* d_in, const int* in_sizes, int n_in, void* d_out,
                              int out_size, void* d_ws, size_t ws_size, hipStream_t stream) {
    const void* video = d_in[0];
    const void* question = d_in[1];
    const int* mask = (const int*)d_in[2];
    const void* pos_emb = d_in[3];
    const void* mod_emb = d_in[4];
    const void* Wv = d_in[5];
    const void* bv = d_in[6];
    const void* nv_g = d_in[7];
    const void* nv_b = d_in[8];
    const void* emb_g = d_in[9];
    const void* emb_b = d_in[10];
    const void* Wq = d_in[11];
    const void* bq = d_in[12];
    const void* Wk = d_in[13];
    const void* bk = d_in[14];
    const void* Wva = d_in[15];
    const void* bva = d_in[16];
    const void* Wo = d_in[17];
    const void* bo = d_in[18];
    const void* ln1_g = d_in[19];
    const void* ln1_b = d_in[20];
    const void* W1 = d_in[21];
    const void* b1 = d_in[22];
    const void* W2 = d_in[23];
    const void* b2 = d_in[24];
    const void* ln2_g = d_in[25];
    const void* ln2_b = d_in[26];

    char* wsb = (char*)d_ws;
    size_t off = 0;
    auto alloc = [&](size_t bytes) -> void* {
        void* p = (void*)(wsb + off);
        off += (bytes + 4095) & ~((size_t)4095);
        return p;
    };
    int* flag = (int*)alloc(16);
    u16* WvT = (u16*)alloc((size_t)Dd * FDd * 2);
    u16 *WqkvT[NL], *WoT[NL], *W1T[NL], *W2T[NL];
    for (int i = 0; i < NL; i++) {
        WqkvT[i] = (u16*)alloc((size_t)3 * Dd * Dd * 2);
        WoT[i] = (u16*)alloc((size_t)Dd * Dd * 2);
        W1T[i] = (u16*)alloc((size_t)FFf * Dd * 2);
        W2T[i] = (u16*)alloc((size_t)Dd * FFf * 2);
    }
    u16* x = (u16*)alloc((size_t)Bb * Ss * Dd * 2);    // 32 MB residual stream (bf16)
    u16* tmp = (u16*)alloc((size_t)Bb * Ss * Dd * 2);  // 32 MB bf16 GEMM out
    char* uni = (char*)alloc((size_t)134217728);       // union region (lifetimes disjoint)
    u16* videob = (u16*)uni;                           // video bf16   [dead after video GEMM]
    u16* qb = (u16*)uni;                               // q            [B,H,S,DH]
    u16* kb = (u16*)(uni + 33554432);                  // k            [B,H,S,DH]
    u16* vtb = (u16*)(uni + 67108864);                 // v^T          [B,H,DH,S]
    u16* ctxb = (u16*)(uni + 100663296);               // ctx          [B,S,D]
    u16* hb = (u16*)uni;                               // FFN hidden   [B,S,FF] (128 MB)

    dim3 tb(32, 8);

    probe_kernel<<<dim3(1), dim3(64), 0, stream>>>(pos_emb, flag);
    convert_kernel<<<dim3(8192), dim3(256), 0, stream>>>(video, videob, (long)Bb * Tt * FDd, flag);

    transpose_kernel<<<dim3(Dd / 32, FDd / 32), tb, 0, stream>>>(Wv, WvT, FDd, Dd, 0L, flag);
    for (int i = 0; i < NL; i++) {
        transpose4_kernel<<<dim3(Dd / 32, Dd / 32, 4), tb, 0, stream>>>(
            Wq, Wk, Wva, Wo, WqkvT[i], WqkvT[i] + (size_t)Dd * Dd,
            WqkvT[i] + (size_t)2 * Dd * Dd, WoT[i], (long)i * Dd * Dd, flag);
        transpose_kernel<<<dim3(FFf / 32, Dd / 32), tb, 0, stream>>>(W1, W1T[i], Dd, FFf,
                                                                     (long)i * Dd * FFf, flag);
        transpose_kernel<<<dim3(Dd / 32, FFf / 32), tb, 0, stream>>>(W2, W2T[i], FFf, Dd,
                                                                     (long)i * FFf * Dd, flag);
    }

    // video projection: [28672,1024] @ [1024,512] -> tmp bf16 (A = video directly if bf16)
    gemm256<0, FDd, Dd><<<dim3(224), dim3(512), 0, stream>>>(
        videob, video, WvT, bv, nullptr, nullptr, 0L, tmp, nullptr, nullptr, Bb * Tt, flag);
    embed_kernel<<<dim3((Bb * Ss) / 4), dim3(256), 0, stream>>>(question, pos_emb, mod_emb, tmp,
                                                                nv_g, nv_b, emb_g, emb_b, x, flag);

    for (int i = 0; i < NL; i++) {
        gemm256<2, Dd, 1536><<<dim3(768), dim3(512), 0, stream>>>(
            x, nullptr, WqkvT[i], bq, bk, bva, (long)i * Dd, qb, kb, vtb, Bb * Ss, flag);
        flash_kernel<<<dim3(2048), dim3(256), 0, stream>>>(qb, kb, vtb, mask, ctxb);
        gemm256<0, Dd, Dd><<<dim3(256), dim3(512), 0, stream>>>(
            ctxb, nullptr, WoT[i], bo, nullptr, nullptr, (long)i * Dd, tmp, nullptr, nullptr,
            Bb * Ss, flag);
        add_ln_kernel<<<dim3((Bb * Ss) / 4), dim3(256), 0, stream>>>(tmp, x, ln1_g, ln1_b,
                                                                     (long)i * Dd, x, 0, flag);
        gemm256<1, Dd, FFf><<<dim3(1024), dim3(512), 0, stream>>>(
            x, nullptr, W1T[i], b1, nullptr, nullptr, (long)i * FFf, hb, nullptr, nullptr,
            Bb * Ss, flag);
        gemm256<0, FFf, Dd><<<dim3(256), dim3(512), 0, stream>>>(
            hb, nullptr, W2T[i], b2, nullptr, nullptr, (long)i * Dd, tmp, nullptr, nullptr,
            Bb * Ss, flag);
        void* dst = (i == NL - 1) ? d_out : (void*)x;
        add_ln_kernel<<<dim3((Bb * Ss) / 4), dim3(256), 0, stream>>>(
            tmp, x, ln2_g, ln2_b, (long)i * Dd, dst, (i == NL - 1) ? 1 : 0, flag);
    }
    (void)in_sizes; (void)n_in; (void)out_size; (void)ws_size;
}